// Round 1
// baseline (616.398 us; speedup 1.0000x reference)
//
#include <hip/hip_runtime.h>
#include <math.h>

#define N_NODES    100000
#define K_NEIGH    32
#define OUT_STRIDE 448   // 3*128 + 64

// ---------------------------------------------------------------------------
// Dense layer: F[n][j] = relu(b[j] + sum_k in[n][k] * W[k][j]),  DOUT = 64.
// Block = 256 threads: 16 rows/block, 16 threads/row, 4 cols/thread (float4).
// W staged in LDS (ds_read_b128 per 4 FMAs); input rows staged in LDS with
// +4 padding so the 4 rows sharing a wave hit distinct banks.
// COPY_X: dense0 also copies the raw x row into out[:, 384:448].
// ---------------------------------------------------------------------------
template <int DIN, bool COPY_X>
__global__ __launch_bounds__(256) void dense_kernel(
    const float* __restrict__ in, int in_stride,
    const float* __restrict__ W, const float* __restrict__ b,
    float* __restrict__ F, float* __restrict__ out)
{
    __shared__ float Wlds[DIN * 64];
    __shared__ float in_lds[16][DIN + 4];   // +4 pad: banks (4r+k)%32 distinct per row

    const int tid = threadIdx.x;
    const int row0 = blockIdx.x * 16;

    // Stage W (DIN*64 floats) — coalesced float4
    for (int i = tid * 4; i < DIN * 64; i += 256 * 4) {
        *(float4*)&Wlds[i] = *(const float4*)&W[i];
    }
    // Stage 16 input rows (16*DIN floats) — coalesced float4
    for (int i = tid * 4; i < 16 * DIN; i += 256 * 4) {
        const int r = i / DIN;
        const int c = i % DIN;
        *(float4*)&in_lds[r][c] =
            *(const float4*)&in[(size_t)(row0 + r) * in_stride + c];
    }
    __syncthreads();

    const int t = tid & 15;   // col group: cols 4t..4t+3
    const int r = tid >> 4;   // row within tile
    const int n = row0 + r;

    float4 acc = *(const float4*)&b[t * 4];
#pragma unroll 8
    for (int k = 0; k < DIN; ++k) {
        const float a = in_lds[r][k];                       // broadcast
        const float4 w = *(const float4*)&Wlds[k * 64 + t * 4];
        acc.x = fmaf(a, w.x, acc.x);
        acc.y = fmaf(a, w.y, acc.y);
        acc.z = fmaf(a, w.z, acc.z);
        acc.w = fmaf(a, w.w, acc.w);
    }
    acc.x = fmaxf(acc.x, 0.f);
    acc.y = fmaxf(acc.y, 0.f);
    acc.z = fmaxf(acc.z, 0.f);
    acc.w = fmaxf(acc.w, 0.f);
    *(float4*)&F[(size_t)n * 64 + t * 4] = acc;

    if (COPY_X) {
        const float4 xv = *(const float4*)&in_lds[r][t * 4];
        *(float4*)&out[(size_t)n * OUT_STRIDE + 384 + t * 4] = xv;
    }
}

// ---------------------------------------------------------------------------
// KNN accumulate: for node n, over k in [0,32):
//   w_k = exp(-10*dist[n][k]);  g = F[idx[n][k]][:]
//   out[n][c]    = mean_k(w_k*g[c]) - F[n][c]
//   out[n][64+c] = max_k (w_k*g[c]) - F[n][c]
// One wave (64 lanes) per node; idx/dist preloaded in lanes 0..31, exp
// computed once per neighbour, broadcast via __shfl. Each gather = one
// coalesced 256B row read.
// ---------------------------------------------------------------------------
__global__ __launch_bounds__(256) void acc_kernel(
    const float* __restrict__ F,
    const int* __restrict__ idx,
    const float* __restrict__ dist,
    float* __restrict__ out)   // already offset to this layer's slab
{
    const int wave = threadIdx.x >> 6;
    const int lane = threadIdx.x & 63;
    const int n = blockIdx.x * 4 + wave;
    if (n >= N_NODES) return;

    int   jv = 0;
    float wv = 0.f;
    if (lane < 32) {
        jv = idx[(size_t)n * K_NEIGH + lane];
        const float d = dist[(size_t)n * K_NEIGH + lane];
        wv = __expf(-10.f * d);
    }

    const float prev = F[(size_t)n * 64 + lane];
    float sum = 0.f;
    float mx  = -INFINITY;

#pragma unroll 4
    for (int k = 0; k < K_NEIGH; ++k) {
        const int   jk = __shfl(jv, k);
        const float wk = __shfl(wv, k);
        const float g  = F[(size_t)jk * 64 + lane];
        const float v  = wk * g;
        sum += v;
        mx = fmaxf(mx, v);
    }

    out[(size_t)n * OUT_STRIDE + lane]      = sum * (1.f / 32.f) - prev;
    out[(size_t)n * OUT_STRIDE + 64 + lane] = mx - prev;
}

// ---------------------------------------------------------------------------
extern "C" void kernel_launch(void* const* d_in, const int* in_sizes, int n_in,
                              void* d_out, int out_size, void* d_ws, size_t ws_size,
                              hipStream_t stream)
{
    const float* x    = (const float*)d_in[0];
    const int*   idx  = (const int*)  d_in[1];
    const float* dist = (const float*)d_in[2];
    const float* W0   = (const float*)d_in[3];
    const float* b0   = (const float*)d_in[4];
    const float* W1   = (const float*)d_in[5];
    const float* b1   = (const float*)d_in[6];
    const float* W2   = (const float*)d_in[7];
    const float* b2   = (const float*)d_in[8];

    float* out = (float*)d_out;
    float* F   = (float*)d_ws;          // N*64 floats = 25.6 MB gather table

    const int dense_grid = N_NODES / 16;      // 6250 (N divisible by 16)
    const int acc_grid   = (N_NODES + 3) / 4; // 25000

    // Layer 0: dense from x (also copies x into out[:,384:448])
    dense_kernel<64, true><<<dense_grid, 256, 0, stream>>>(x, 64, W0, b0, F, out);
    acc_kernel<<<acc_grid, 256, 0, stream>>>(F, idx, dist, out + 0);

    // Layer 1: dense reads layer-0 slab of out (it IS the next input)
    dense_kernel<128, false><<<dense_grid, 256, 0, stream>>>(out + 0, OUT_STRIDE, W1, b1, F, nullptr);
    acc_kernel<<<acc_grid, 256, 0, stream>>>(F, idx, dist, out + 128);

    // Layer 2
    dense_kernel<128, false><<<dense_grid, 256, 0, stream>>>(out + 128, OUT_STRIDE, W2, b2, F, nullptr);
    acc_kernel<<<acc_grid, 256, 0, stream>>>(F, idx, dist, out + 256);
}

// Round 2
// 505.637 us; speedup vs baseline: 1.2191x; 1.2191x over previous
//
#include <hip/hip_runtime.h>
#include <math.h>

#define N_NODES    100000
#define K_NEIGH    32
#define OUT_STRIDE 448   // 3*128 + 64

// bf16 helpers (RNE, matches numpy/JAX cast semantics for finite values)
static __device__ __forceinline__ unsigned short f2bf(float f) {
    unsigned int u = __float_as_uint(f);
    unsigned int r = (u + 0x7FFFu + ((u >> 16) & 1u)) >> 16;
    return (unsigned short)r;
}
static __device__ __forceinline__ float bf2f(unsigned short h) {
    return __uint_as_float(((unsigned int)h) << 16);
}

// ---------------------------------------------------------------------------
// Dense layer: F[n][c] = relu(b[c] + sum_k in[n][k] * W[k][c]), DOUT=64,
// F stored bf16.
//
// Layout: block = 256 threads = 4 waves; tile = 64 rows.
//   lane (0..63) = row within tile; wave w handles cols [16w, 16w+16).
// Input tile staged TRANSPOSED in LDS: aT[k][row], row-stride 65 words so
// element-wise staging (consecutive tid -> consecutive c at fixed row) hits
// bank (c + r) % 32 -> conflict-free, and the compute read aT[k][lane] is
// contiguous across lanes -> conflict-free broadcast-free b32.
// W is read at a WAVE-UNIFORM address (c0 forced uniform via readfirstlane)
// -> compiler scalarizes to s_load; the FMA uses the 1-SGPR-operand slot.
// Per k per wave: 1 ds_read_b32 (5.8 cyc) + 16 v_fmac (32 cyc) -> VALU-bound.
// COPY_X: dense0 also copies the raw x row into out[:, 384:448].
// ---------------------------------------------------------------------------
template <int DIN, bool COPY_X>
__global__ __launch_bounds__(256) void dense_kernel(
    const float* __restrict__ in, int in_stride,
    const float* __restrict__ W, const float* __restrict__ b,
    unsigned short* __restrict__ F, float* __restrict__ out)
{
    __shared__ float aT[DIN][65];

    const int tid  = threadIdx.x;
    const int row0 = blockIdx.x * 64;

    // Stage transposed input tile (coalesced global b32, conflict-free LDS)
    for (int i = tid; i < 64 * DIN; i += 256) {
        const int r = i >> (DIN == 64 ? 6 : 7);
        const int c = i & (DIN - 1);
        const int n = row0 + r;
        float v = 0.f;
        if (n < N_NODES) {
            v = in[(size_t)n * in_stride + c];
            if (COPY_X) out[(size_t)n * OUT_STRIDE + 384 + c] = v;
        }
        aT[c][r] = v;
    }
    __syncthreads();

    const int lane = tid & 63;                                    // row
    const int c0   = __builtin_amdgcn_readfirstlane((tid >> 6) * 16); // col base (SGPR)
    const int n    = row0 + lane;

    float acc[16];
#pragma unroll
    for (int c = 0; c < 16; ++c) acc[c] = b[c0 + c];

#pragma unroll 4
    for (int k = 0; k < DIN; ++k) {
        const float a = aT[k][lane];                 // 1 conflict-free b32
        const float* __restrict__ wrow = &W[(size_t)k * 64 + c0];
#pragma unroll
        for (int c = 0; c < 16; ++c)
            acc[c] = fmaf(a, wrow[c], acc[c]);       // v_fmac v, s, v
    }

    if (n < N_NODES) {
        // relu -> bf16 pack -> two 16B stores (32B contiguous per lane)
        unsigned int u[8];
#pragma unroll
        for (int c = 0; c < 16; c += 2) {
            const unsigned int lo = f2bf(fmaxf(acc[c], 0.f));
            const unsigned int hi = f2bf(fmaxf(acc[c + 1], 0.f));
            u[c >> 1] = lo | (hi << 16);
        }
        uint4* dst = (uint4*)&F[(size_t)n * 64 + c0];  // 32B-aligned (c0 % 16 == 0)
        dst[0] = make_uint4(u[0], u[1], u[2], u[3]);
        dst[1] = make_uint4(u[4], u[5], u[6], u[7]);
    }
}

// ---------------------------------------------------------------------------
// KNN accumulate (F in bf16): for node n, over k in [0,32):
//   w_k = exp(-10*dist[n][k]);  g = F[idx[n][k]][:]
//   out[n][c]    = mean_k(w_k*g[c]) - F[n][c]
//   out[n][64+c] = max_k (w_k*g[c]) - F[n][c]
// One wave per node; idx/dist in lanes 0..31, broadcast via __shfl.
// Each gather = one coalesced 128B row read (bf16 rows).
// ---------------------------------------------------------------------------
__global__ __launch_bounds__(256) void acc_kernel(
    const unsigned short* __restrict__ F,
    const int* __restrict__ idx,
    const float* __restrict__ dist,
    float* __restrict__ out)   // already offset to this layer's slab
{
    const int wave = threadIdx.x >> 6;
    const int lane = threadIdx.x & 63;
    const int n = blockIdx.x * 4 + wave;
    if (n >= N_NODES) return;

    int   jv = 0;
    float wv = 0.f;
    if (lane < 32) {
        jv = idx[(size_t)n * K_NEIGH + lane];
        wv = __expf(-10.f * dist[(size_t)n * K_NEIGH + lane]);
    }

    const float prev = bf2f(F[(size_t)n * 64 + lane]);
    float sum = 0.f;
    float mx  = -INFINITY;

#pragma unroll 8
    for (int k = 0; k < K_NEIGH; ++k) {
        const int   jk = __shfl(jv, k);
        const float wk = __shfl(wv, k);
        const float g  = bf2f(F[(size_t)jk * 64 + lane]);
        const float v  = wk * g;
        sum += v;
        mx = fmaxf(mx, v);
    }

    out[(size_t)n * OUT_STRIDE + lane]      = sum * (1.f / 32.f) - prev;
    out[(size_t)n * OUT_STRIDE + 64 + lane] = mx - prev;
}

// ---------------------------------------------------------------------------
extern "C" void kernel_launch(void* const* d_in, const int* in_sizes, int n_in,
                              void* d_out, int out_size, void* d_ws, size_t ws_size,
                              hipStream_t stream)
{
    const float* x    = (const float*)d_in[0];
    const int*   idx  = (const int*)  d_in[1];
    const float* dist = (const float*)d_in[2];
    const float* W0   = (const float*)d_in[3];
    const float* b0   = (const float*)d_in[4];
    const float* W1   = (const float*)d_in[5];
    const float* b1   = (const float*)d_in[6];
    const float* W2   = (const float*)d_in[7];
    const float* b2   = (const float*)d_in[8];

    float* out = (float*)d_out;
    unsigned short* F = (unsigned short*)d_ws;   // N*64 bf16 = 12.8 MB gather table

    const int dense_grid = (N_NODES + 63) / 64;  // 1563
    const int acc_grid   = N_NODES / 4;          // 25000

    // Layer 0: dense from x (also copies x into out[:,384:448])
    dense_kernel<64, true><<<dense_grid, 256, 0, stream>>>(x, 64, W0, b0, F, out);
    acc_kernel<<<acc_grid, 256, 0, stream>>>(F, idx, dist, out + 0);

    // Layer 1: dense reads layer-0 slab of out (it IS the next input)
    dense_kernel<128, false><<<dense_grid, 256, 0, stream>>>(out + 0, OUT_STRIDE, W1, b1, F, nullptr);
    acc_kernel<<<acc_grid, 256, 0, stream>>>(F, idx, dist, out + 128);

    // Layer 2
    dense_kernel<128, false><<<dense_grid, 256, 0, stream>>>(out + 128, OUT_STRIDE, W2, b2, F, nullptr);
    acc_kernel<<<acc_grid, 256, 0, stream>>>(F, idx, dist, out + 256);
}

// Round 3
// 422.330 us; speedup vs baseline: 1.4595x; 1.1973x over previous
//
#include <hip/hip_runtime.h>
#include <math.h>

#define N_NODES    100000
#define K_NEIGH    32
#define OUT_STRIDE 448   // 3*128 + 64

typedef __attribute__((ext_vector_type(8))) __bf16 bf16x8;
typedef __attribute__((ext_vector_type(4))) float  f32x4;

// bf16 helpers (RNE)
static __device__ __forceinline__ unsigned short f2bf(float f) {
    unsigned int u = __float_as_uint(f);
    return (unsigned short)((u + 0x7FFFu + ((u >> 16) & 1u)) >> 16);
}
static __device__ __forceinline__ float bf2f(unsigned short h) {
    return __uint_as_float(((unsigned int)h) << 16);
}

// ---------------------------------------------------------------------------
// One-shot prep: wtab[n][k] = exp(-10*dist[n][k])  (reused by all 3 acc passes)
// and bf16 transposed weights Wt[n][k] = bf16(W[k][n]) for the MFMA dense.
// ---------------------------------------------------------------------------
__global__ __launch_bounds__(256) void prep_kernel(
    const float* __restrict__ dist, float* __restrict__ wtab,
    const float* __restrict__ W0, const float* __restrict__ W1,
    const float* __restrict__ W2,
    unsigned short* __restrict__ Wt0, unsigned short* __restrict__ Wt1,
    unsigned short* __restrict__ Wt2)
{
    const int i = blockIdx.x * 256 + threadIdx.x;
    if (i < N_NODES * K_NEIGH) wtab[i] = __expf(-10.f * dist[i]);
    if (i < 64 * 64)  Wt0[(i & 63) * 64  + (i >> 6)] = f2bf(W0[i]);  // i = k*64+n
    if (i < 128 * 64) Wt1[(i & 63) * 128 + (i >> 6)] = f2bf(W1[i]);
    if (i < 128 * 64) Wt2[(i & 63) * 128 + (i >> 6)] = f2bf(W2[i]);
}

// ---------------------------------------------------------------------------
// Dense layer via MFMA: F[n][c] = relu(b[c] + sum_k in[n][k]*W[k][c]), bf16 out.
// Block = 256 (4 waves), tile = 64 rows. Wave w: rows [16w,16w+16), all 64 cols
// via 4 N-blocks of 16x16x32 MFMA. A and Wt staged bf16 in LDS, K-stride
// padded +8 bf16 so b128 frag reads are ~2-way (free) on banks.
// Frag layouts (m89-verified): A[m=lane&15][k=(lane>>4)*8+j];
// B[k=(lane>>4)*8+j][n=lane&15]; C: col=lane&15, row=(lane>>4)*4+reg.
// COPY_X: dense0 also copies the raw x row into out[:, 384:448].
// ---------------------------------------------------------------------------
template <int DIN, bool COPY_X>
__global__ __launch_bounds__(256) void dense_kernel(
    const float* __restrict__ in, int in_stride,
    const unsigned short* __restrict__ Wt,   // [64][DIN] bf16 (transposed W)
    const float* __restrict__ b,
    unsigned short* __restrict__ F, float* __restrict__ out)
{
    constexpr int LDK = DIN + 8;
    __shared__ unsigned short aLDS[64 * LDK];
    __shared__ unsigned short bLDS[64 * LDK];

    const int tid  = threadIdx.x;
    const int row0 = blockIdx.x * 64;

    // Stage A: 64 rows x DIN fp32 -> bf16 (coalesced float4 reads)
    for (int i = tid; i < 64 * (DIN / 4); i += 256) {
        const int r = i / (DIN / 4);
        const int c = (i % (DIN / 4)) * 4;
        const int n = row0 + r;
        float4 v = make_float4(0.f, 0.f, 0.f, 0.f);
        if (n < N_NODES) {
            v = *(const float4*)&in[(size_t)n * in_stride + c];
            if (COPY_X) *(float4*)&out[(size_t)n * OUT_STRIDE + 384 + c] = v;
        }
        const unsigned int u0 = (unsigned int)f2bf(v.x) | ((unsigned int)f2bf(v.y) << 16);
        const unsigned int u1 = (unsigned int)f2bf(v.z) | ((unsigned int)f2bf(v.w) << 16);
        *(uint2*)&aLDS[r * LDK + c] = make_uint2(u0, u1);
    }
    // Stage B: Wt [64][DIN] bf16 -> padded LDS (b128 copies)
    for (int i = tid; i < 64 * (DIN / 8); i += 256) {
        const int nn = i / (DIN / 8);
        const int k0 = (i % (DIN / 8)) * 8;
        *(uint4*)&bLDS[nn * LDK + k0] = *(const uint4*)&Wt[nn * DIN + k0];
    }
    __syncthreads();

    const int lane = tid & 63;
    const int wv   = tid >> 6;
    const int m    = lane & 15;
    const int quad = lane >> 4;

    f32x4 acc[4];
#pragma unroll
    for (int nb = 0; nb < 4; ++nb) acc[nb] = (f32x4){0.f, 0.f, 0.f, 0.f};

#pragma unroll
    for (int ks = 0; ks < DIN / 32; ++ks) {
        const int koff = ks * 32 + quad * 8;
        const bf16x8 afr =
            *reinterpret_cast<const bf16x8*>(&aLDS[(wv * 16 + m) * LDK + koff]);
#pragma unroll
        for (int nb = 0; nb < 4; ++nb) {
            const bf16x8 bfr =
                *reinterpret_cast<const bf16x8*>(&bLDS[(nb * 16 + m) * LDK + koff]);
            acc[nb] = __builtin_amdgcn_mfma_f32_16x16x32_bf16(afr, bfr, acc[nb], 0, 0, 0);
        }
    }

    // Epilogue: bias + relu + bf16 store
#pragma unroll
    for (int nb = 0; nb < 4; ++nb) {
        const int c    = nb * 16 + m;
        const float bc = b[c];
#pragma unroll
        for (int reg = 0; reg < 4; ++reg) {
            const int n = row0 + wv * 16 + quad * 4 + reg;
            if (n < N_NODES) {
                const float vv = fmaxf(acc[nb][reg] + bc, 0.f);
                F[(size_t)n * 64 + c] = f2bf(vv);
            }
        }
    }
}

// ---------------------------------------------------------------------------
// KNN accumulate (F bf16, weights precomputed): one wave per node.
// n is wave-uniform -> idx row + wtab row load as s_load (SGPRs); NO shuffles,
// NO exp in the hot loop. Each gather = one coalesced 128B bf16 row read.
// ---------------------------------------------------------------------------
__global__ __launch_bounds__(256) void acc_kernel(
    const unsigned short* __restrict__ F,
    const int* __restrict__ idx,
    const float* __restrict__ wtab,
    float* __restrict__ out)   // already offset to this layer's slab
{
    const int wv   = __builtin_amdgcn_readfirstlane(threadIdx.x >> 6);
    const int lane = threadIdx.x & 63;
    const int n    = blockIdx.x * 4 + wv;          // wave-uniform

    const float prev = bf2f(F[(size_t)n * 64 + lane]);
    float sum = 0.f;
    float mx  = -INFINITY;

#pragma unroll
    for (int k = 0; k < K_NEIGH; ++k) {
        const int   jk = idx [(size_t)n * K_NEIGH + k];   // uniform -> SGPR
        const float wk = wtab[(size_t)n * K_NEIGH + k];   // uniform -> SGPR
        const float g  = bf2f(F[(size_t)jk * 64 + lane]);
        const float v  = wk * g;
        sum += v;
        mx = fmaxf(mx, v);
    }

    out[(size_t)n * OUT_STRIDE + lane]      = sum * (1.f / 32.f) - prev;
    out[(size_t)n * OUT_STRIDE + 64 + lane] = mx - prev;
}

// ---------------------------------------------------------------------------
extern "C" void kernel_launch(void* const* d_in, const int* in_sizes, int n_in,
                              void* d_out, int out_size, void* d_ws, size_t ws_size,
                              hipStream_t stream)
{
    const float* x    = (const float*)d_in[0];
    const int*   idx  = (const int*)  d_in[1];
    const float* dist = (const float*)d_in[2];
    const float* W0   = (const float*)d_in[3];
    const float* b0   = (const float*)d_in[4];
    const float* W1   = (const float*)d_in[5];
    const float* b1   = (const float*)d_in[6];
    const float* W2   = (const float*)d_in[7];
    const float* b2   = (const float*)d_in[8];

    float* out = (float*)d_out;

    // Workspace layout (all 16B-aligned):
    char* ws = (char*)d_ws;
    unsigned short* F    = (unsigned short*)(ws);                    // 12.8 MB
    float*          wtab = (float*)         (ws + 12800000);         // 12.8 MB
    unsigned short* Wt0  = (unsigned short*)(ws + 25600000);         // 8 KB
    unsigned short* Wt1  = (unsigned short*)(ws + 25608192);         // 16 KB
    unsigned short* Wt2  = (unsigned short*)(ws + 25624576);         // 16 KB

    const int prep_grid  = (N_NODES * K_NEIGH + 255) / 256;  // 12500
    const int dense_grid = (N_NODES + 63) / 64;              // 1563
    const int acc_grid   = N_NODES / 4;                      // 25000

    prep_kernel<<<prep_grid, 256, 0, stream>>>(dist, wtab, W0, W1, W2, Wt0, Wt1, Wt2);

    // Layer 0: dense from x (also copies x into out[:,384:448])
    dense_kernel<64, true><<<dense_grid, 256, 0, stream>>>(x, 64, Wt0, b0, F, out);
    acc_kernel<<<acc_grid, 256, 0, stream>>>(F, idx, wtab, out + 0);

    // Layer 1: dense reads layer-0 slab of out (it IS the next input)
    dense_kernel<128, false><<<dense_grid, 256, 0, stream>>>(out + 0, OUT_STRIDE, Wt1, b1, F, nullptr);
    acc_kernel<<<acc_grid, 256, 0, stream>>>(F, idx, wtab, out + 128);

    // Layer 2
    dense_kernel<128, false><<<dense_grid, 256, 0, stream>>>(out + 128, OUT_STRIDE, Wt2, b2, F, nullptr);
    acc_kernel<<<acc_grid, 256, 0, stream>>>(F, idx, wtab, out + 256);
}